// Round 2
// baseline (307.175 us; speedup 1.0000x reference)
//
#include <hip/hip_runtime.h>
#include <stdint.h>

#define N_NODES  50000
#define K_DIM    128
#define OUT_DIM  32
#define N_EDGES  1600000
#define NPAD     50176            // 196 * 256, zero-padded node count
#define NCB      196              // count blocks for scan

// -------- h = x @ W : [50000,128] x [128,32] -> [50000,32] --------
__global__ __launch_bounds__(256) void gemm_kernel(const float* __restrict__ x,
                                                   const float* __restrict__ w,
                                                   float* __restrict__ h) {
    __shared__ float wlds[K_DIM * OUT_DIM];
    const int t = threadIdx.x;
    #pragma unroll
    for (int i = 0; i < (K_DIM * OUT_DIM) / 256; ++i)
        wlds[i * 256 + t] = w[i * 256 + t];
    __syncthreads();

    const int row = blockIdx.x * 8 + (t >> 5);
    const int col = t & 31;
    if (row >= N_NODES) return;

    const float4* x4 = reinterpret_cast<const float4*>(x + (size_t)row * K_DIM);
    float acc = 0.f;
    #pragma unroll
    for (int k4 = 0; k4 < K_DIM / 4; ++k4) {
        float4 xv = x4[k4];
        const int k = k4 * 4;
        acc += xv.x * wlds[(k + 0) * OUT_DIM + col];
        acc += xv.y * wlds[(k + 1) * OUT_DIM + col];
        acc += xv.z * wlds[(k + 2) * OUT_DIM + col];
        acc += xv.w * wlds[(k + 3) * OUT_DIM + col];
    }
    h[(size_t)row * OUT_DIM + col] = acc;
}

// -------- CSR build: histogram over dst --------
__global__ __launch_bounds__(256) void hist_kernel(const int* __restrict__ edst,
                                                   int* __restrict__ counts) {
    const int e = blockIdx.x * 256 + threadIdx.x;
    if (e >= N_EDGES) return;
    atomicAdd(&counts[edst[e]], 1);
}

// -------- scan step 1: per-block sums of counts --------
__global__ __launch_bounds__(256) void scan_bsum_kernel(const int* __restrict__ counts,
                                                        int* __restrict__ bsums) {
    __shared__ int r[256];
    const int t = threadIdx.x;
    r[t] = counts[blockIdx.x * 256 + t];
    __syncthreads();
    #pragma unroll
    for (int d = 128; d > 0; d >>= 1) {
        if (t < d) r[t] += r[t + d];
        __syncthreads();
    }
    if (t == 0) bsums[blockIdx.x] = r[0];
}

// -------- scan step 2: serial exclusive scan of 196 block sums --------
__global__ void scan_top_kernel(int* __restrict__ bsums) {
    if (threadIdx.x == 0) {
        int run = 0;
        for (int b = 0; b < NCB; ++b) {
            int c = bsums[b];
            bsums[b] = run;
            run += c;
        }
    }
}

// -------- scan step 3: per-block exclusive scan + base; write offsets & cursor --------
__global__ __launch_bounds__(256) void scan_fin_kernel(const int* __restrict__ counts,
                                                       const int* __restrict__ bsums,
                                                       int* __restrict__ offsets,
                                                       int* __restrict__ cursor) {
    __shared__ int s[256];
    const int t = threadIdx.x;
    const int i = blockIdx.x * 256 + t;
    const int v = counts[i];
    s[t] = v;
    __syncthreads();
    #pragma unroll
    for (int d = 1; d < 256; d <<= 1) {
        int xv = 0;
        if (t >= d) xv = s[t - d];
        __syncthreads();
        if (t >= d) s[t] += xv;
        __syncthreads();
    }
    const int excl = bsums[blockIdx.x] + s[t] - v;   // exclusive prefix
    offsets[i] = excl;
    cursor[i]  = excl;
}

// -------- fill: counting-sort edges into dst-grouped (src,weight) pairs --------
__global__ __launch_bounds__(256) void fill_kernel(const int*   __restrict__ esrc,
                                                   const int*   __restrict__ edst,
                                                   const float* __restrict__ ew,
                                                   int*         __restrict__ cursor,
                                                   uint64_t*    __restrict__ pairs) {
    const int e = blockIdx.x * 256 + threadIdx.x;
    if (e >= N_EDGES) return;
    const int d   = edst[e];
    const int pos = atomicAdd(&cursor[d], 1);
    const uint64_t pr = ((uint64_t)__float_as_uint(ew[e]) << 32) | (uint32_t)esrc[e];
    pairs[pos] = pr;
}

// -------- pull: 32 lanes per node, register accumulation, no float atomics --------
__global__ __launch_bounds__(256) void pull_kernel(const int*      __restrict__ offsets,
                                                   const int*      __restrict__ counts,
                                                   const uint64_t* __restrict__ pairs,
                                                   const float*    __restrict__ h,
                                                   float*          __restrict__ out) {
    const long long gid = (long long)blockIdx.x * 256 + threadIdx.x;
    const int node = (int)(gid >> 5);
    const int col  = (int)(gid & 31);
    if (node >= N_NODES) return;

    const int beg = offsets[node];
    const int cnt = counts[node];
    float acc = 0.f;
    for (int j = 0; j < cnt; ++j) {
        const uint64_t pr = pairs[beg + j];
        const int   src = (int)(uint32_t)(pr & 0xffffffffu);
        const float w   = __uint_as_float((uint32_t)(pr >> 32));
        acc += w * h[(size_t)src * OUT_DIM + col];
    }
    out[(size_t)node * OUT_DIM + col] = acc;
}

// -------- fallback scatter (R1 path) if workspace too small --------
__global__ __launch_bounds__(256) void scatter_kernel(const int*   __restrict__ esrc,
                                                      const int*   __restrict__ edst,
                                                      const float* __restrict__ ew,
                                                      const float* __restrict__ h,
                                                      float*       out) {
    const long long gid = (long long)blockIdx.x * blockDim.x + threadIdx.x;
    const int e   = (int)(gid >> 5);
    const int col = (int)(gid & 31);
    if (e >= N_EDGES) return;
    const int   s = esrc[e];
    const int   d = edst[e];
    const float w = ew[e];
    atomicAdd(out + (size_t)d * OUT_DIM + col, w * h[(size_t)s * OUT_DIM + col]);
}

extern "C" void kernel_launch(void* const* d_in, const int* in_sizes, int n_in,
                              void* d_out, int out_size, void* d_ws, size_t ws_size,
                              hipStream_t stream) {
    const float* x    = (const float*)d_in[0];
    const float* w    = (const float*)d_in[1];
    const int*   esrc = (const int*)d_in[2];
    const int*   edst = (const int*)d_in[3];
    const float* ew   = (const float*)d_in[4];
    float*       out  = (float*)d_out;

    // workspace layout
    const size_t PAIRS_B = (size_t)N_EDGES * 8;            // 12,800,000
    const size_t H_B     = (size_t)N_NODES * OUT_DIM * 4;  //  6,400,000
    const size_t CNT_B   = (size_t)NPAD * 4;               //    200,704
    const size_t REQ     = PAIRS_B + H_B + 3 * CNT_B + 1024;

    if (ws_size >= REQ) {
        uint64_t* pairs   = (uint64_t*)d_ws;
        float*    h       = (float*)((char*)d_ws + PAIRS_B);
        int*      counts  = (int*)((char*)d_ws + PAIRS_B + H_B);
        int*      offsets = counts + NPAD;
        int*      cursor  = offsets + NPAD;
        int*      bsums   = cursor + NPAD;

        gemm_kernel<<<(N_NODES + 7) / 8, 256, 0, stream>>>(x, w, h);

        hipMemsetAsync(counts, 0, CNT_B, stream);
        hist_kernel<<<(N_EDGES + 255) / 256, 256, 0, stream>>>(edst, counts);
        scan_bsum_kernel<<<NCB, 256, 0, stream>>>(counts, bsums);
        scan_top_kernel<<<1, 64, 0, stream>>>(bsums);
        scan_fin_kernel<<<NCB, 256, 0, stream>>>(counts, bsums, offsets, cursor);
        fill_kernel<<<(N_EDGES + 255) / 256, 256, 0, stream>>>(esrc, edst, ew, cursor, pairs);

        const long long total = (long long)N_NODES * OUT_DIM;
        pull_kernel<<<(int)((total + 255) / 256), 256, 0, stream>>>(offsets, counts, pairs, h, out);
    } else {
        // fallback: R1 atomic scatter
        float* h = (float*)d_ws;
        hipMemsetAsync(d_out, 0, (size_t)out_size * sizeof(float), stream);
        gemm_kernel<<<(N_NODES + 7) / 8, 256, 0, stream>>>(x, w, h);
        const long long total = (long long)N_EDGES * OUT_DIM;
        scatter_kernel<<<(int)((total + 255) / 256), 256, 0, stream>>>(esrc, edst, ew, h, out);
    }
}